// Round 1
// baseline (435.912 us; speedup 1.0000x reference)
//
#include <hip/hip_runtime.h>
#include <math.h>

// ---------------- problem constants ----------------
#define NCLS 19
#define DD   128
#define EPSV 1e-7f
#define LOGEPS -16.118095651f   // ln(1e-7)

// ---------------- workspace layout (float indices) ----------------
#define OFF_TAU    0
#define OFF_CNTL   8      // 19
#define OFF_WSUMU  32     // 19
#define OFF_CNTU   64     // 19
#define OFF_CE     96     // 4
#define OFF_VALID  100    // 4
#define OFF_UCPS   104    // 1
#define OFF_SUML   128    // 19*128 = 2432
#define OFF_SUMU   2560   // 2432
#define OFF_MEM    4992   // 2432
#define OFF_INIT   7424   // 19
#define OFF_RUD    7456   // 4*128*128 = 65536
#define OFF_PSEUDO 72992  // 65536 ints
#define ZERO_N     72992  // zero [0, OFF_PSEUDO)

__device__ __forceinline__ void fatom(float* p, float v) { unsafeAtomicAdd(p, v); }

// ---------------- kZ: zero accumulators + tau_high ----------------
__global__ __launch_bounds__(256) void kZ(float* __restrict__ W,
                                          const int* __restrict__ cur_it,
                                          const int* __restrict__ max_it) {
    int i = blockIdx.x * 256 + threadIdx.x;
    if (i == 0) {
        int mi = max_it[0]; if (mi < 1) mi = 1;
        double ratio = (double)cur_it[0] / (double)mi;
        W[OFF_TAU] = (float)(0.85 - (0.85 - 0.5) * cos(M_PI * ratio * 0.5));
    } else if (i < ZERO_N) {
        W[i] = 0.0f;
    }
}

// ---------------- kB v4: streaming argmax + block compaction ----------------
// Key fact: r_u = 0 unless argmax(logits_u1) == argmax(logits_u2) (~1/19 of
// pixels for random logits). Phase 1 streams both tensors computing ONLY the
// online argmax (tiny register state, values discarded -> high occupancy,
// pure memory stream). Agreeing pixels are compacted into LDS; phase 2
// re-gathers their 19x2 values (L2-resident: ~78 KB/block) and computes
// s/kl/ce/r_u in exactly the original accumulation order.
// grid 2048 x 256: block = one image row (b = blk>>9, h = blk&511),
// thread t owns pixels w = 2t, 2t+1 (float2 channel loads).
__global__ __launch_bounds__(256, 6) void kB(const float* __restrict__ lu1,
                                             const float* __restrict__ lu2,
                                             float* __restrict__ W) {
    __shared__ unsigned int sPk[512];   // (w<<5) | label
    __shared__ float sM1[512], sM2[512];
    __shared__ unsigned int sCnt;
    __shared__ float sCE;

    float* rud = W + OFF_RUD;
    int* pseudo = (int*)(W + OFF_PSEUDO);

    int blk = blockIdx.x;
    int b = blk >> 9;
    int h = blk & 511;
    int t = threadIdx.x;
    if (t == 0) { sCnt = 0u; sCE = 0.f; }
    __syncthreads();

    size_t base = (size_t)b * (NCLS * 262144) + (size_t)h * 512;
    const float2* p1 = (const float2*)(lu1 + base) + t;   // channel stride: 131072 float2
    const float2* p2 = (const float2*)(lu2 + base) + t;

    // ---- phase 1: online argmax only (state: 4 floats + 4 labels) ----
    float m1a, m1b, m2a, m2b;
    int y1a = 0, y1b = 0, y2a = 0, y2b = 0;
    {
        float2 x1 = p1[0], x2 = p2[0];
        m1a = x1.x; m1b = x1.y; m2a = x2.x; m2b = x2.y;
    }
#pragma unroll
    for (int c = 1; c < NCLS; c++) {
        float2 x1 = p1[(size_t)c * 131072];
        float2 x2 = p2[(size_t)c * 131072];
        if (x1.x > m1a) { m1a = x1.x; y1a = c; }
        if (x1.y > m1b) { m1b = x1.y; y1b = c; }
        if (x2.x > m2a) { m2a = x2.x; y2a = c; }
        if (x2.y > m2b) { m2b = x2.y; y2b = c; }
    }

    int wa = t << 1, wb = wa + 1;
    bool aga = (y1a == y2a), agb = (y1b == y2b);

    // nearest-down pseudo consensus at (h%4==0, w%4==0): wa%4==0 iff t even
    if ((h & 3) == 0 && (t & 1) == 0)
        pseudo[b * 16384 + (h >> 2) * 128 + (wa >> 2)] = aga ? y1a : 0;

    if (aga) {
        unsigned int i = atomicAdd(&sCnt, 1u);
        sPk[i] = ((unsigned)wa << 5) | (unsigned)y1a;
        sM1[i] = m1a; sM2[i] = m2a;
    }
    if (agb) {
        unsigned int i = atomicAdd(&sCnt, 1u);
        sPk[i] = ((unsigned)wb << 5) | (unsigned)y1b;
        sM1[i] = m1b; sM2[i] = m2b;
    }
    __syncthreads();

    // ---- phase 2: heavy path on compacted agreeing pixels (~27/block) ----
    int n = (int)sCnt;
    int hm = h & 3;
    for (int i = t; i < n; i += 256) {
        unsigned pk = sPk[i];
        int w = (int)(pk >> 5), y = (int)(pk & 31u);
        float m1 = sM1[i], m2 = sM2[i];
        const float* q1 = lu1 + base + w;
        const float* q2 = lu2 + base + w;

        float s1 = 0.f, s2 = 0.f, l1y = 0.f, l2y = 0.f;
#pragma unroll
        for (int c = 0; c < NCLS; c++) {
            float x1 = q1[(size_t)c * 262144];
            float x2 = q2[(size_t)c * 262144];
            s1 += __expf(x1 - m1);
            s2 += __expf(x2 - m2);
            if (c == y) { l1y = x1; l2y = x2; }
        }
        float lse1 = m1 + __logf(s1);
        float lse2 = m2 + __logf(s2);

        float kl = 0.f;
#pragma unroll
        for (int c = 0; c < NCLS; c++) {
            float x1 = q1[(size_t)c * 262144];
            float x2 = q2[(size_t)c * 262144];
            float lq1 = x1 - lse1, lq2 = x2 - lse2;
            float e1 = __expf(lq1), e2 = __expf(lq2);
            float mm = 0.5f * (e1 + e2);
            float lm = __logf(fmaxf(mm, EPSV));
            kl += e1 * (fmaxf(lq1, LOGEPS) - lm) + e2 * (fmaxf(lq2, LOGEPS) - lm);
        }
        float conf = 0.5f * (1.f / s1 + 1.f / s2);
        float r_u = conf * __expf(-0.5f * kl);
        float ce = (lse1 - l1y) + (lse2 - l2y);
        fatom(&sCE, r_u * ce);
        // bilinear 4x down touches rows/cols {1,2} mod 4 only
        if ((hm == 1 || hm == 2) && ((w & 3) == 1 || (w & 3) == 2))
            fatom(&rud[b * 16384 + (h >> 2) * 128 + (w >> 2)], 0.25f * r_u);
    }
    __syncthreads();
    if (t == 0) fatom(&W[OFF_UCPS], sCE);
}

// ---------------- kC v3: transposed segment-sum; accU -> direct global -------
// grid 512 x 256. Block owns 128 consecutive pixels (4 tiles of 32).
// Thread (pg = tid>>7, d = tid&127) exclusively owns accum column (pg, :, d).
__global__ __launch_bounds__(256) void kC(const float* __restrict__ fl1,
                                          const float* __restrict__ fl2,
                                          const float* __restrict__ fu1,
                                          const float* __restrict__ fu2,
                                          const int* __restrict__ gt,
                                          float* __restrict__ W) {
    __shared__ float tile[DD * 33];        // [d][p], pad 33 -> bank (d+p)%32
    __shared__ float accL[2 * NCLS * DD];  // [pg][c][d]
    __shared__ int   sLab[32], sCu[32];
    __shared__ float sW[32];
    __shared__ float sCntL[NCLS], sCntU[NCLS], sWUs[NCLS];

    int tid = threadIdx.x;
    for (int i = tid; i < 2 * NCLS * DD; i += 256) accL[i] = 0.f;
    if (tid < NCLS) { sCntL[tid] = 0.f; sCntU[tid] = 0.f; sWUs[tid] = 0.f; }
    __syncthreads();

    int P0 = blockIdx.x * 128;             // flat pixel start (b*16384 + rem)
    int b = P0 >> 14;
    const float tau = W[OFF_TAU];
    const float* rud = W + OFF_RUD;
    const int* pseudo = (const int*)(W + OFF_PSEUDO);
    size_t gb = (size_t)b * 2097152;

    int d = tid & 127, pg = tid >> 7;

    for (int T = 0; T < 4; T++) {
        int rem0 = (P0 + T * 32) & 16383;
        // ---- label/weight phase (32 threads) ----
        if (tid < 32) {
            int rem = rem0 + tid;
            int bp = b * 16384 + rem;
            int ii = rem >> 7, jj = rem & 127;
            int cl = gt[b * 262144 + ii * 2048 + jj * 4];
            int cu = pseudo[bp];
            float rd = rud[bp];
            float w = (rd > tau) ? rd : 0.f;
            sLab[tid] = cl; sCu[tid] = cu; sW[tid] = w;
            fatom(&sCntL[cl], 1.f);
            fatom(&sCntU[cu], 1.f);
            if (w > 0.f) fatom(&sWUs[cu], w);
        }
        // ---- stage 32x128 tile: float4 global, scalar LDS (2-way alias only) --
        for (int i = tid; i < 1024; i += 256) {
            int dd = i >> 3, p4 = (i & 7) << 2;
            size_t g = gb + (size_t)dd * 16384 + rem0 + p4;
            float4 x1 = *(const float4*)(fl1 + g);
            float4 x2 = *(const float4*)(fl2 + g);
            float* tp = &tile[dd * 33 + p4];
            tp[0] = 0.5f * (x1.x + x2.x);
            tp[1] = 0.5f * (x1.y + x2.y);
            tp[2] = 0.5f * (x1.z + x2.z);
            tp[3] = 0.5f * (x1.w + x2.w);
        }
        __syncthreads();
        // ---- transposed accumulate: zero atomics in hot loop ----
        float* aL = &accL[pg * (NCLS * DD) + d];
#pragma unroll
        for (int p = pg * 16; p < pg * 16 + 16; p++) {
            int c = sLab[p];
            aL[c * DD] += tile[d * 33 + p];
            float w = sW[p];
            if (w > 0.f) {                 // wave-uniform, rare: direct global
                size_t g = gb + (size_t)d * 16384 + rem0 + p;
                fatom(&W[OFF_SUMU + sCu[p] * DD + d], w * 0.5f * (fu1[g] + fu2[g]));
            }
        }
        __syncthreads();
    }
    // ---- flush per-block partials ----
    for (int i = tid; i < NCLS * DD; i += 256)
        fatom(&W[OFF_SUML + i], accL[i] + accL[NCLS * DD + i]);
    if (tid < NCLS) {
        fatom(&W[OFF_CNTL + tid], sCntL[tid]);
        fatom(&W[OFF_WSUMU + tid], sWUs[tid]);
        fatom(&W[OFF_CNTU + tid], sCntU[tid]);
    }
}

// ---------------- kD: finalize prototypes + memory update ----------------
// grid 19 x 128 (one block per class, one thread per d)
__global__ __launch_bounds__(128) void kD(const float* __restrict__ mem,
                                          const unsigned char* __restrict__ minit,
                                          float* __restrict__ W) {
    int c = blockIdx.x, d = threadIdx.x;
    __shared__ float red[128];
    float cntL = W[OFF_CNTL + c], wsU = W[OFF_WSUMU + c], cntU = W[OFF_CNTU + c];
    bool plp = cntL >= 1.f, pup = cntU >= 1.f;
    float pl = W[OFF_SUML + c * DD + d] / (cntL + EPSV);
    float pu = W[OFF_SUMU + c * DD + d] / (wsU + EPSV);
    float merged = (plp && pup) ? (0.7f * pl + 0.3f * pu) : (plp ? pl : pu);

    red[d] = merged * merged; __syncthreads();
    for (int s = 64; s > 0; s >>= 1) { if (d < s) red[d] += red[d + s]; __syncthreads(); }
    float nrm = red[0];
    __syncthreads();
    float pn = merged / fmaxf(sqrtf(nrm), 1e-12f);

    float mo = mem[c * DD + d];
    float e = 0.999f * mo + 0.001f * pn;
    red[d] = e * e; __syncthreads();
    for (int s = 64; s > 0; s >>= 1) { if (d < s) red[d] += red[d + s]; __syncthreads(); }
    float ne = red[0];
    float ema = e / fmaxf(sqrtf(ne), 1e-12f);

    bool present = plp || pup;
    bool init = (minit[c] != 0);   // all-False input: zero bytes either dtype width
    float nm = present ? (init ? ema : pn) : mo;
    W[OFF_MEM + c * DD + d] = nm;
    if (d == 0) W[OFF_INIT + c] = (init || present) ? 1.f : 0.f;
}

// ---------------- kE: hard contrastive for 4 feats ----------------
__device__ __forceinline__ void pix_loss(const float dots[NCLS], float nn, int lab,
                                         const float* sInit, float& ce_acc, float& v_acc) {
    float inv = 5.0f / fmaxf(sqrtf(nn), 1e-12f);   // 1/TAU_HARD = 5
    float lg[NCLS];
#pragma unroll
    for (int c = 0; c < NCLS; c++) lg[c] = dots[c] * inv;
    float mx = lg[0];
#pragma unroll
    for (int c = 1; c < NCLS; c++) mx = fmaxf(mx, lg[c]);
    float s = 0.f;
#pragma unroll
    for (int c = 0; c < NCLS; c++) s += __expf(lg[c] - mx);
    float lse = mx + __logf(s);
    float ll = lg[0];
#pragma unroll
    for (int c = 1; c < NCLS; c++) if (c == lab) ll = lg[c];
    float vld = sInit[lab];
    ce_acc += vld * (lse - ll);
    v_acc += vld;
}

// grid (128, 4) x 256; thread handles pixels p0 and p0+256 of feat blockIdx.y
__global__ __launch_bounds__(256) void kE(const float* __restrict__ f0,
                                          const float* __restrict__ f1,
                                          const float* __restrict__ f2,
                                          const float* __restrict__ f3,
                                          const int* __restrict__ gt,
                                          float* __restrict__ W) {
    __shared__ __align__(16) float sMem[NCLS * DD];
    __shared__ float sInit[NCLS];
    __shared__ float redA[256], redB[256];
    int fid = blockIdx.y;
    const float* feat = (fid == 0) ? f0 : (fid == 1) ? f1 : (fid == 2) ? f2 : f3;
    for (int i = threadIdx.x; i < NCLS * DD; i += 256) sMem[i] = W[OFF_MEM + i];
    if (threadIdx.x < NCLS) sInit[threadIdx.x] = W[OFF_INIT + threadIdx.x];
    __syncthreads();

    int p0 = blockIdx.x * 512 + threadIdx.x;   // second pixel = p0 + 256 (same b)
    int b = p0 >> 14;
    int rem0 = p0 & 16383;
    const float* fp = feat + (size_t)b * 2097152 + rem0;

    float dots0[NCLS], dots1[NCLS];
#pragma unroll
    for (int c = 0; c < NCLS; c++) { dots0[c] = 0.f; dots1[c] = 0.f; }
    float n0 = 0.f, n1 = 0.f;

    for (int d0 = 0; d0 < DD; d0 += 8) {
        const float* fpp = fp + (size_t)d0 * 16384;
        float a[8], bb[8];
#pragma unroll
        for (int j = 0; j < 8; j++) {
            a[j]  = fpp[(size_t)j * 16384];
            bb[j] = fpp[(size_t)j * 16384 + 256];
        }
#pragma unroll
        for (int j = 0; j < 8; j++) { n0 += a[j] * a[j]; n1 += bb[j] * bb[j]; }
#pragma unroll
        for (int c = 0; c < NCLS; c++) {
            float4 m0 = *(const float4*)&sMem[c * DD + d0];
            float4 m1 = *(const float4*)&sMem[c * DD + d0 + 4];
            dots0[c] += a[0] * m0.x + a[1] * m0.y + a[2] * m0.z + a[3] * m0.w
                      + a[4] * m1.x + a[5] * m1.y + a[6] * m1.z + a[7] * m1.w;
            dots1[c] += bb[0] * m0.x + bb[1] * m0.y + bb[2] * m0.z + bb[3] * m0.w
                      + bb[4] * m1.x + bb[5] * m1.y + bb[6] * m1.z + bb[7] * m1.w;
        }
    }

    const int* pseudo = (const int*)(W + OFF_PSEUDO);
    int rem1 = rem0 + 256;
    int lab0 = (fid < 2) ? gt[b * 262144 + (rem0 >> 7) * 2048 + (rem0 & 127) * 4] : pseudo[p0];
    int lab1 = (fid < 2) ? gt[b * 262144 + (rem1 >> 7) * 2048 + (rem1 & 127) * 4] : pseudo[p0 + 256];

    float ce_acc = 0.f, v_acc = 0.f;
    pix_loss(dots0, n0, lab0, sInit, ce_acc, v_acc);
    pix_loss(dots1, n1, lab1, sInit, ce_acc, v_acc);

    redA[threadIdx.x] = ce_acc;
    redB[threadIdx.x] = v_acc;
    __syncthreads();
    for (int s = 128; s > 0; s >>= 1) {
        if (threadIdx.x < s) { redA[threadIdx.x] += redA[threadIdx.x + s]; redB[threadIdx.x] += redB[threadIdx.x + s]; }
        __syncthreads();
    }
    if (threadIdx.x == 0) {
        fatom(&W[OFF_CE + fid], redA[0]);
        fatom(&W[OFF_VALID + fid], redB[0]);
    }
}

// ---------------- kF: combine -> d_out[2] ----------------
__global__ void kF(float* __restrict__ out, const float* __restrict__ W) {
    if (threadIdx.x == 0 && blockIdx.x == 0) {
        float h[4];
#pragma unroll
        for (int i = 0; i < 4; i++) {
            float nv = W[OFF_VALID + i];
            h[i] = (nv > 0.f) ? W[OFF_CE + i] / fmaxf(nv, 1.f) : 0.f;
        }
        out[0] = 0.5f * (h[0] + h[1]) + 0.5f * (h[2] + h[3]);   // loss_dgpc
        out[1] = W[OFF_UCPS] * (1.0f / 1048576.0f);             // loss_ucps
    }
}

extern "C" void kernel_launch(void* const* d_in, const int* in_sizes, int n_in,
                              void* d_out, int out_size, void* d_ws, size_t ws_size,
                              hipStream_t stream) {
    const float* fl1 = (const float*)d_in[0];
    const float* fl2 = (const float*)d_in[1];
    const float* fu1 = (const float*)d_in[2];
    const float* fu2 = (const float*)d_in[3];
    // d_in[4], d_in[5] (logits_l1/l2) are unused by the reference
    const float* lu1 = (const float*)d_in[6];
    const float* lu2 = (const float*)d_in[7];
    const float* mem = (const float*)d_in[8];
    const int* gt = (const int*)d_in[9];
    const unsigned char* minit = (const unsigned char*)d_in[10];
    const int* cur = (const int*)d_in[11];
    const int* mxi = (const int*)d_in[12];
    float* W = (float*)d_ws;
    float* out = (float*)d_out;

    kZ<<<286, 256, 0, stream>>>(W, cur, mxi);
    kB<<<2048, 256, 0, stream>>>(lu1, lu2, W);
    kC<<<512, 256, 0, stream>>>(fl1, fl2, fu1, fu2, gt, W);
    kD<<<NCLS, 128, 0, stream>>>(mem, minit, W);
    kE<<<dim3(128, 4), 256, 0, stream>>>(fl1, fl2, fu1, fu2, gt, W);
    kF<<<1, 64, 0, stream>>>(out, W);
}

// Round 2
// 393.370 us; speedup vs baseline: 1.1081x; 1.1081x over previous
//
#include <hip/hip_runtime.h>
#include <math.h>

// ---------------- problem constants ----------------
#define NCLS 19
#define DD   128
#define EPSV 1e-7f
#define LOGEPS -16.118095651f   // ln(1e-7)

// ---------------- workspace layout (float indices) ----------------
#define OFF_TAU    0
#define OFF_CNTL   8      // 19
#define OFF_WSUMU  32     // 19
#define OFF_CNTU   64     // 19
#define OFF_CE     96     // 4
#define OFF_VALID  100    // 4
#define OFF_UCPS   104    // 1
#define OFF_SUML   128    // 19*128 = 2432
#define OFF_SUMU   2560   // 2432
#define OFF_MEM    4992   // 2432
#define OFF_INIT   7424   // 19
#define OFF_RUD    7456   // 4*128*128 = 65536
#define OFF_PSEUDO 72992  // 65536 ints
#define ZERO_N     72992  // zero [0, OFF_PSEUDO)

__device__ __forceinline__ void fatom(float* p, float v) { unsafeAtomicAdd(p, v); }

// ---------------- kZ: zero accumulators + tau_high ----------------
__global__ __launch_bounds__(256) void kZ(float* __restrict__ W,
                                          const int* __restrict__ cur_it,
                                          const int* __restrict__ max_it) {
    int i = blockIdx.x * 256 + threadIdx.x;
    if (i == 0) {
        int mi = max_it[0]; if (mi < 1) mi = 1;
        double ratio = (double)cur_it[0] / (double)mi;
        W[OFF_TAU] = (float)(0.85 - (0.85 - 0.5) * cos(M_PI * ratio * 0.5));
    } else if (i < ZERO_N) {
        W[i] = 0.0f;
    }
}

// ---------------- kB v5: LDS-staged argmax + compacted heavy path ----------
// Post-mortem of v4: phase-2 global re-gather cost +54 MB HBM (cache-line
// granularity misses) and the online-argmax serial chain at VGPR=40 starved
// memory-level parallelism (1.6 TB/s). v5: stage the block's 38 channel
// planes into LDS via ~10 independent float4 loads/thread (deep MLP, fully
// coalesced), then argmax + compaction + heavy path all from LDS. Zero
// global refetch; per-pixel math identical to reference.
// grid 1024 x 256: block = 256 consecutive pixels (b = blk>>8).
// LDS 39 KB tile + 1 KB -> 4 blocks/CU (50% occupancy), grid exactly fills.
__global__ __launch_bounds__(256, 4) void kB(const float* __restrict__ lu1,
                                             const float* __restrict__ lu2,
                                             float* __restrict__ W) {
    __shared__ float tile[38 * 256];     // [c][p]; c<19: lu1, c>=19: lu2
    __shared__ unsigned int sPk[256];    // (p<<5) | label
    __shared__ unsigned int sCnt;
    __shared__ float sCE;

    float* rud = W + OFF_RUD;
    int* pseudo = (int*)(W + OFF_PSEUDO);

    int t = threadIdx.x;
    int blk = blockIdx.x;
    int b = blk >> 8;
    int rem = (blk & 255) << 8;          // flat pixel offset within image
    int row = rem >> 9;                  // image row (0..511)
    int col0 = rem & 511;                // 0 or 256

    if (t == 0) { sCnt = 0u; sCE = 0.f; }

    // ---- stage: 38 planes x 256 px, float4, wave-uniform plane per load ----
    size_t base = (size_t)b * (NCLS * 262144) + rem;
    for (int i = t; i < 38 * 64; i += 256) {
        int c = i >> 6;                  // wave-uniform (64-aligned chunks)
        int g = (i & 63) << 2;
        const float* src = (c < NCLS) ? (lu1 + base + (size_t)c * 262144)
                                      : (lu2 + base + (size_t)(c - NCLS) * 262144);
        float4 v = *(const float4*)(src + g);
        *(float4*)&tile[c * 256 + g] = v;
    }
    __syncthreads();

    // ---- phase 1: per-pixel argmax from LDS (stride-1 lanes: conflict-free) --
    float m1 = tile[t], m2 = tile[NCLS * 256 + t];
    int y1 = 0, y2 = 0;
#pragma unroll
    for (int c = 1; c < NCLS; c++) {
        float x1 = tile[c * 256 + t];
        float x2 = tile[(NCLS + c) * 256 + t];
        if (x1 > m1) { m1 = x1; y1 = c; }
        if (x2 > m2) { m2 = x2; y2 = c; }
    }
    int w = col0 + t;
    bool ag = (y1 == y2);

    // nearest-down pseudo consensus at (row%4==0, w%4==0)
    if ((row & 3) == 0 && (t & 3) == 0)
        pseudo[b * 16384 + (row >> 2) * 128 + (w >> 2)] = ag ? y1 : 0;

    if (ag) {
        unsigned int i = atomicAdd(&sCnt, 1u);
        sPk[i] = ((unsigned)t << 5) | (unsigned)y1;
    }
    __syncthreads();

    // ---- phase 2: heavy path on compacted agreeing pixels (~13/block) ----
    int n = (int)sCnt;
    int rm = row & 3;
    for (int i = t; i < n; i += 256) {
        unsigned pk = sPk[i];
        int p = (int)(pk >> 5), y = (int)(pk & 31u);
        const float* q1 = &tile[p];
        const float* q2 = &tile[NCLS * 256 + p];

        // recompute maxes (cheap, few active lanes; saves 2 KB LDS)
        float mm1 = q1[0], mm2 = q2[0];
#pragma unroll
        for (int c = 1; c < NCLS; c++) {
            mm1 = fmaxf(mm1, q1[c * 256]);
            mm2 = fmaxf(mm2, q2[c * 256]);
        }
        float s1 = 0.f, s2 = 0.f, l1y = 0.f, l2y = 0.f;
#pragma unroll
        for (int c = 0; c < NCLS; c++) {
            float x1 = q1[c * 256];
            float x2 = q2[c * 256];
            s1 += __expf(x1 - mm1);
            s2 += __expf(x2 - mm2);
            if (c == y) { l1y = x1; l2y = x2; }
        }
        float lse1 = mm1 + __logf(s1);
        float lse2 = mm2 + __logf(s2);

        float kl = 0.f;
#pragma unroll
        for (int c = 0; c < NCLS; c++) {
            float x1 = q1[c * 256];
            float x2 = q2[c * 256];
            float lq1 = x1 - lse1, lq2 = x2 - lse2;
            float e1 = __expf(lq1), e2 = __expf(lq2);
            float mmid = 0.5f * (e1 + e2);
            float lm = __logf(fmaxf(mmid, EPSV));
            kl += e1 * (fmaxf(lq1, LOGEPS) - lm) + e2 * (fmaxf(lq2, LOGEPS) - lm);
        }
        float conf = 0.5f * (1.f / s1 + 1.f / s2);
        float r_u = conf * __expf(-0.5f * kl);
        float ce = (lse1 - l1y) + (lse2 - l2y);
        fatom(&sCE, r_u * ce);
        int wp = col0 + p;
        // bilinear 4x down touches rows/cols {1,2} mod 4 only
        if ((rm == 1 || rm == 2) && ((wp & 3) == 1 || (wp & 3) == 2))
            fatom(&rud[b * 16384 + (row >> 2) * 128 + (wp >> 2)], 0.25f * r_u);
    }
    __syncthreads();
    if (t == 0) fatom(&W[OFF_UCPS], sCE);
}

// ---------------- kC v3: transposed segment-sum; accU -> direct global -------
// grid 512 x 256. Block owns 128 consecutive pixels (4 tiles of 32).
// Thread (pg = tid>>7, d = tid&127) exclusively owns accum column (pg, :, d).
__global__ __launch_bounds__(256) void kC(const float* __restrict__ fl1,
                                          const float* __restrict__ fl2,
                                          const float* __restrict__ fu1,
                                          const float* __restrict__ fu2,
                                          const int* __restrict__ gt,
                                          float* __restrict__ W) {
    __shared__ float tile[DD * 33];        // [d][p], pad 33 -> bank (d+p)%32
    __shared__ float accL[2 * NCLS * DD];  // [pg][c][d]
    __shared__ int   sLab[32], sCu[32];
    __shared__ float sW[32];
    __shared__ float sCntL[NCLS], sCntU[NCLS], sWUs[NCLS];

    int tid = threadIdx.x;
    for (int i = tid; i < 2 * NCLS * DD; i += 256) accL[i] = 0.f;
    if (tid < NCLS) { sCntL[tid] = 0.f; sCntU[tid] = 0.f; sWUs[tid] = 0.f; }
    __syncthreads();

    int P0 = blockIdx.x * 128;             // flat pixel start (b*16384 + rem)
    int b = P0 >> 14;
    const float tau = W[OFF_TAU];
    const float* rud = W + OFF_RUD;
    const int* pseudo = (const int*)(W + OFF_PSEUDO);
    size_t gb = (size_t)b * 2097152;

    int d = tid & 127, pg = tid >> 7;

    for (int T = 0; T < 4; T++) {
        int rem0 = (P0 + T * 32) & 16383;
        // ---- label/weight phase (32 threads) ----
        if (tid < 32) {
            int rem = rem0 + tid;
            int bp = b * 16384 + rem;
            int ii = rem >> 7, jj = rem & 127;
            int cl = gt[b * 262144 + ii * 2048 + jj * 4];
            int cu = pseudo[bp];
            float rd = rud[bp];
            float w = (rd > tau) ? rd : 0.f;
            sLab[tid] = cl; sCu[tid] = cu; sW[tid] = w;
            fatom(&sCntL[cl], 1.f);
            fatom(&sCntU[cu], 1.f);
            if (w > 0.f) fatom(&sWUs[cu], w);
        }
        // ---- stage 32x128 tile: float4 global, scalar LDS (2-way alias only) --
        for (int i = tid; i < 1024; i += 256) {
            int dd = i >> 3, p4 = (i & 7) << 2;
            size_t g = gb + (size_t)dd * 16384 + rem0 + p4;
            float4 x1 = *(const float4*)(fl1 + g);
            float4 x2 = *(const float4*)(fl2 + g);
            float* tp = &tile[dd * 33 + p4];
            tp[0] = 0.5f * (x1.x + x2.x);
            tp[1] = 0.5f * (x1.y + x2.y);
            tp[2] = 0.5f * (x1.z + x2.z);
            tp[3] = 0.5f * (x1.w + x2.w);
        }
        __syncthreads();
        // ---- transposed accumulate: zero atomics in hot loop ----
        float* aL = &accL[pg * (NCLS * DD) + d];
#pragma unroll
        for (int p = pg * 16; p < pg * 16 + 16; p++) {
            int c = sLab[p];
            aL[c * DD] += tile[d * 33 + p];
            float w = sW[p];
            if (w > 0.f) {                 // wave-uniform, rare: direct global
                size_t g = gb + (size_t)d * 16384 + rem0 + p;
                fatom(&W[OFF_SUMU + sCu[p] * DD + d], w * 0.5f * (fu1[g] + fu2[g]));
            }
        }
        __syncthreads();
    }
    // ---- flush per-block partials ----
    for (int i = tid; i < NCLS * DD; i += 256)
        fatom(&W[OFF_SUML + i], accL[i] + accL[NCLS * DD + i]);
    if (tid < NCLS) {
        fatom(&W[OFF_CNTL + tid], sCntL[tid]);
        fatom(&W[OFF_WSUMU + tid], sWUs[tid]);
        fatom(&W[OFF_CNTU + tid], sCntU[tid]);
    }
}

// ---------------- kD: finalize prototypes + memory update ----------------
// grid 19 x 128 (one block per class, one thread per d)
__global__ __launch_bounds__(128) void kD(const float* __restrict__ mem,
                                          const unsigned char* __restrict__ minit,
                                          float* __restrict__ W) {
    int c = blockIdx.x, d = threadIdx.x;
    __shared__ float red[128];
    float cntL = W[OFF_CNTL + c], wsU = W[OFF_WSUMU + c], cntU = W[OFF_CNTU + c];
    bool plp = cntL >= 1.f, pup = cntU >= 1.f;
    float pl = W[OFF_SUML + c * DD + d] / (cntL + EPSV);
    float pu = W[OFF_SUMU + c * DD + d] / (wsU + EPSV);
    float merged = (plp && pup) ? (0.7f * pl + 0.3f * pu) : (plp ? pl : pu);

    red[d] = merged * merged; __syncthreads();
    for (int s = 64; s > 0; s >>= 1) { if (d < s) red[d] += red[d + s]; __syncthreads(); }
    float nrm = red[0];
    __syncthreads();
    float pn = merged / fmaxf(sqrtf(nrm), 1e-12f);

    float mo = mem[c * DD + d];
    float e = 0.999f * mo + 0.001f * pn;
    red[d] = e * e; __syncthreads();
    for (int s = 64; s > 0; s >>= 1) { if (d < s) red[d] += red[d + s]; __syncthreads(); }
    float ne = red[0];
    float ema = e / fmaxf(sqrtf(ne), 1e-12f);

    bool present = plp || pup;
    bool init = (minit[c] != 0);   // all-False input: zero bytes either dtype width
    float nm = present ? (init ? ema : pn) : mo;
    W[OFF_MEM + c * DD + d] = nm;
    if (d == 0) W[OFF_INIT + c] = (init || present) ? 1.f : 0.f;
}

// ---------------- kE: hard contrastive for 4 feats ----------------
__device__ __forceinline__ void pix_loss(const float dots[NCLS], float nn, int lab,
                                         const float* sInit, float& ce_acc, float& v_acc) {
    float inv = 5.0f / fmaxf(sqrtf(nn), 1e-12f);   // 1/TAU_HARD = 5
    float lg[NCLS];
#pragma unroll
    for (int c = 0; c < NCLS; c++) lg[c] = dots[c] * inv;
    float mx = lg[0];
#pragma unroll
    for (int c = 1; c < NCLS; c++) mx = fmaxf(mx, lg[c]);
    float s = 0.f;
#pragma unroll
    for (int c = 0; c < NCLS; c++) s += __expf(lg[c] - mx);
    float lse = mx + __logf(s);
    float ll = lg[0];
#pragma unroll
    for (int c = 1; c < NCLS; c++) if (c == lab) ll = lg[c];
    float vld = sInit[lab];
    ce_acc += vld * (lse - ll);
    v_acc += vld;
}

// grid (128, 4) x 256; thread handles pixels p0 and p0+256 of feat blockIdx.y
__global__ __launch_bounds__(256) void kE(const float* __restrict__ f0,
                                          const float* __restrict__ f1,
                                          const float* __restrict__ f2,
                                          const float* __restrict__ f3,
                                          const int* __restrict__ gt,
                                          float* __restrict__ W) {
    __shared__ __align__(16) float sMem[NCLS * DD];
    __shared__ float sInit[NCLS];
    __shared__ float redA[256], redB[256];
    int fid = blockIdx.y;
    const float* feat = (fid == 0) ? f0 : (fid == 1) ? f1 : (fid == 2) ? f2 : f3;
    for (int i = threadIdx.x; i < NCLS * DD; i += 256) sMem[i] = W[OFF_MEM + i];
    if (threadIdx.x < NCLS) sInit[threadIdx.x] = W[OFF_INIT + threadIdx.x];
    __syncthreads();

    int p0 = blockIdx.x * 512 + threadIdx.x;   // second pixel = p0 + 256 (same b)
    int b = p0 >> 14;
    int rem0 = p0 & 16383;
    const float* fp = feat + (size_t)b * 2097152 + rem0;

    float dots0[NCLS], dots1[NCLS];
#pragma unroll
    for (int c = 0; c < NCLS; c++) { dots0[c] = 0.f; dots1[c] = 0.f; }
    float n0 = 0.f, n1 = 0.f;

    for (int d0 = 0; d0 < DD; d0 += 8) {
        const float* fpp = fp + (size_t)d0 * 16384;
        float a[8], bb[8];
#pragma unroll
        for (int j = 0; j < 8; j++) {
            a[j]  = fpp[(size_t)j * 16384];
            bb[j] = fpp[(size_t)j * 16384 + 256];
        }
#pragma unroll
        for (int j = 0; j < 8; j++) { n0 += a[j] * a[j]; n1 += bb[j] * bb[j]; }
#pragma unroll
        for (int c = 0; c < NCLS; c++) {
            float4 m0 = *(const float4*)&sMem[c * DD + d0];
            float4 m1 = *(const float4*)&sMem[c * DD + d0 + 4];
            dots0[c] += a[0] * m0.x + a[1] * m0.y + a[2] * m0.z + a[3] * m0.w
                      + a[4] * m1.x + a[5] * m1.y + a[6] * m1.z + a[7] * m1.w;
            dots1[c] += bb[0] * m0.x + bb[1] * m0.y + bb[2] * m0.z + bb[3] * m0.w
                      + bb[4] * m1.x + bb[5] * m1.y + bb[6] * m1.z + bb[7] * m1.w;
        }
    }

    const int* pseudo = (const int*)(W + OFF_PSEUDO);
    int rem1 = rem0 + 256;
    int lab0 = (fid < 2) ? gt[b * 262144 + (rem0 >> 7) * 2048 + (rem0 & 127) * 4] : pseudo[p0];
    int lab1 = (fid < 2) ? gt[b * 262144 + (rem1 >> 7) * 2048 + (rem1 & 127) * 4] : pseudo[p0 + 256];

    float ce_acc = 0.f, v_acc = 0.f;
    pix_loss(dots0, n0, lab0, sInit, ce_acc, v_acc);
    pix_loss(dots1, n1, lab1, sInit, ce_acc, v_acc);

    redA[threadIdx.x] = ce_acc;
    redB[threadIdx.x] = v_acc;
    __syncthreads();
    for (int s = 128; s > 0; s >>= 1) {
        if (threadIdx.x < s) { redA[threadIdx.x] += redA[threadIdx.x + s]; redB[threadIdx.x] += redB[threadIdx.x + s]; }
        __syncthreads();
    }
    if (threadIdx.x == 0) {
        fatom(&W[OFF_CE + fid], redA[0]);
        fatom(&W[OFF_VALID + fid], redB[0]);
    }
}

// ---------------- kF: combine -> d_out[2] ----------------
__global__ void kF(float* __restrict__ out, const float* __restrict__ W) {
    if (threadIdx.x == 0 && blockIdx.x == 0) {
        float h[4];
#pragma unroll
        for (int i = 0; i < 4; i++) {
            float nv = W[OFF_VALID + i];
            h[i] = (nv > 0.f) ? W[OFF_CE + i] / fmaxf(nv, 1.f) : 0.f;
        }
        out[0] = 0.5f * (h[0] + h[1]) + 0.5f * (h[2] + h[3]);   // loss_dgpc
        out[1] = W[OFF_UCPS] * (1.0f / 1048576.0f);             // loss_ucps
    }
}

extern "C" void kernel_launch(void* const* d_in, const int* in_sizes, int n_in,
                              void* d_out, int out_size, void* d_ws, size_t ws_size,
                              hipStream_t stream) {
    const float* fl1 = (const float*)d_in[0];
    const float* fl2 = (const float*)d_in[1];
    const float* fu1 = (const float*)d_in[2];
    const float* fu2 = (const float*)d_in[3];
    // d_in[4], d_in[5] (logits_l1/l2) are unused by the reference
    const float* lu1 = (const float*)d_in[6];
    const float* lu2 = (const float*)d_in[7];
    const float* mem = (const float*)d_in[8];
    const int* gt = (const int*)d_in[9];
    const unsigned char* minit = (const unsigned char*)d_in[10];
    const int* cur = (const int*)d_in[11];
    const int* mxi = (const int*)d_in[12];
    float* W = (float*)d_ws;
    float* out = (float*)d_out;

    kZ<<<286, 256, 0, stream>>>(W, cur, mxi);
    kB<<<1024, 256, 0, stream>>>(lu1, lu2, W);
    kC<<<512, 256, 0, stream>>>(fl1, fl2, fu1, fu2, gt, W);
    kD<<<NCLS, 128, 0, stream>>>(mem, minit, W);
    kE<<<dim3(128, 4), 256, 0, stream>>>(fl1, fl2, fu1, fu2, gt, W);
    kF<<<1, 64, 0, stream>>>(out, W);
}